// Round 6
// baseline (64.414 us; speedup 1.0000x reference)
//
#include <hip/hip_runtime.h>

#define IMGSZ 448.0f
#define HH 28
#define WW 28
#define AA 5
#define CC 80
#define BB 128
#define NN 50
#define HW (HH * WW)
#define NCELL (BB * AA * HW)          // 501760
#define NBOX  (BB * NN)               // 6400
#define NOOBJ_BLKS 256                // grid-stride blocks for conf channel
#define BOX_BLKS  (NBOX / 4)          // 1600 (4 waves/block, 1 box/wave)
#define NBLK (NOOBJ_BLKS + BOX_BLKS)  // 1856
#define SEGQ (HW / 4)                 // 196 float4s per (b,a) conf channel

__device__ __forceinline__ float sigf(float x) {
    return 1.0f / (1.0f + __expf(-x));
}

// compute (best_anchor, gi, gj) for one box
__device__ __forceinline__ int cell_of(const float* __restrict__ anc,
                                       float bx, float by, float bw, float bh,
                                       int* pgi, int* pgj) {
    float gtw = bw * IMGSZ, gth = bh * IMGSZ;
    float gt_area = gtw * gth;
    int best = 0;
    float best_iou = -1.0f;
    #pragma unroll
    for (int k = 0; k < AA; ++k) {
        float aw = anc[2 * k], ah = anc[2 * k + 1];
        float inter = fminf(gtw, aw) * fminf(gth, ah);
        float iou = inter / (gt_area + aw * ah - inter);
        if (iou > best_iou) { best_iou = iou; best = k; }
    }
    float gx = bx * WW, gy = by * HH;
    int gi = (int)gx; gi = gi < 0 ? 0 : (gi > WW - 1 ? WW - 1 : gi);
    int gj = (int)gy; gj = gj < 0 ? 0 : (gj > HH - 1 ? HH - 1 : gj);
    *pgi = gi; *pgj = gj;
    return best;
}

// ---- single fused kernel: noobj + wave-per-box + last-block finalize ----
// No contended double atomics: per-block partial via uncontended atomicExch
// (device-scope, distinct addresses); one native u32 atomicAdd per block on
// the counter. Finalize condition (old+1) % NBLK == 0 is start-value
// independent -> immune to the 0xAA workspace poison (no zeroing kernel).
__global__ void fused_kernel(const float* __restrict__ out,
                             const float* __restrict__ boxes,
                             const int* __restrict__ cls,
                             const float* __restrict__ anchors,
                             double* __restrict__ partials,
                             unsigned int* __restrict__ cnt,
                             float* __restrict__ final_out) {
    double v = 0.0;
    int blk = blockIdx.x;

    if (blk < NOOBJ_BLKS) {
        // noobj baseline: 0.5*sigmoid(conf)^2 over all cells, float4 grid-stride
        const int NQ = NCELL / 4;          // 125440; SEGQ=196 float4 per (b,a)
        for (int q = blk * 256 + threadIdx.x; q < NQ; q += NOOBJ_BLKS * 256) {
            int seg = q / SEGQ;            // which (b,a), 0..639
            int off = q - seg * SEGQ;
            const float4* p = (const float4*)(out + ((size_t)seg * 85 + 4) * HW) + off;
            float4 x = *p;
            float s0 = sigf(x.x), s1 = sigf(x.y), s2 = sigf(x.z), s3 = sigf(x.w);
            v += 0.5 * (double)(s0 * s0) + 0.5 * (double)(s1 * s1)
               + 0.5 * (double)(s2 * s2) + 0.5 * (double)(s3 * s3);
        }
    } else {
        // one wave per GT box: 4 waves/block
        int lane = threadIdx.x & 63;
        int u = (blk - NOOBJ_BLKS) * 4 + (threadIdx.x >> 6);   // box idx < 6400
        int b = u / NN, n = u - b * NN;

        float anc[2 * AA];
        #pragma unroll
        for (int i = 0; i < 2 * AA; ++i) anc[i] = anchors[i];

        const float* bx0 = boxes + (size_t)u * 4;
        float bx = bx0[0], by = bx0[1], bw = bx0[2], bh = bx0[3];
        int gi, gj;
        int best = cell_of(anc, bx, by, bw, bh, &gi, &gj);

        // issue ALL scattered loads for this box up front (always safe)
        size_t base = ((size_t)(b * AA + best) * 85) * HW + (size_t)gj * WW + gi;
        const float* cl = out + base + 5 * HW;
        float val0 = cl[(size_t)lane * HW];                            // classes 0..63
        float val1 = (lane < 16) ? cl[(size_t)(64 + lane) * HW] : -3.4e38f; // 64..79
        float pch  = (lane < 5) ? out[base + (size_t)lane * HW] : 0.0f;     // tx..conf
        int tc = cls[u];

        // dedup while loads are in flight (last-write-wins: largest n keeps cell)
        bool conflict = false;
        int n2 = n + 1 + lane;
        if (n2 < NN) {
            const float* bp = boxes + (size_t)(b * NN + n2) * 4;
            int gi2, gj2;
            int best2 = cell_of(anc, bp[0], bp[1], bp[2], bp[3], &gi2, &gj2);
            conflict = (best2 == best && gi2 == gi && gj2 == gj);
        }
        bool alive = (__ballot(conflict) == 0ULL);

        if (alive) {
            // 80-class log-softmax, lane-parallel
            float m = fmaxf(val0, val1);
            #pragma unroll
            for (int o = 32; o > 0; o >>= 1) m = fmaxf(m, __shfl_xor(m, o, 64));
            float se = __expf(val0 - m) + ((lane < 16) ? __expf(val1 - m) : 0.0f);
            #pragma unroll
            for (int o = 32; o > 0; o >>= 1) se += __shfl_xor(se, o, 64);
            float lse = m + logf(se);

            float contrib = 0.0f;
            if (lane == 0)       contrib += lse;   // nll = lse - logit_tc
            if (tc == lane)      contrib -= val0;
            if (tc == 64 + lane) contrib -= val1;  // only lanes <16 can hit

            if (lane < 5) {
                if (lane == 0) {
                    float ptx = sigf(pch), tx = bx * WW - (float)gi;
                    contrib += 5.0f * (ptx - tx) * (ptx - tx);
                } else if (lane == 1) {
                    float pty = sigf(pch), ty = by * HH - (float)gj;
                    contrib += 5.0f * (pty - ty) * (pty - ty);
                } else if (lane == 2) {
                    float tw = logf(bw * WW / (anc[2 * best] / 16.0f) + 1e-16f);
                    contrib += 5.0f * (pch - tw) * (pch - tw);
                } else if (lane == 3) {
                    float th = logf(bh * HH / (anc[2 * best + 1] / 16.0f) + 1e-16f);
                    contrib += 5.0f * (pch - th) * (pch - th);
                } else {
                    float pc = sigf(pch);
                    // obj conf term minus the noobj 0.5*pc^2 added by baseline
                    contrib += (pc - 1.0f) * (pc - 1.0f) - 0.5f * pc * pc;
                }
            }
            v = (double)contrib;
        }
    }

    // ---- block reduction (4 waves of 64) ----
    #pragma unroll
    for (int o = 32; o > 0; o >>= 1) v += __shfl_down(v, o, 64);
    __shared__ double s[4];
    __shared__ int done;
    int lane = threadIdx.x & 63, wid = threadIdx.x >> 6;
    if (lane == 0) s[wid] = v;
    __syncthreads();

    if (threadIdx.x == 0) {
        double tsum = s[0] + s[1] + s[2] + s[3];
        // uncontended device-scope publish of this block's partial
        atomicExch((unsigned long long*)(partials + blk),
                   (unsigned long long)__double_as_longlong(tsum));
        __threadfence();   // release: partial visible before counter bump
        unsigned int old = atomicAdd(cnt, 1u);
        done = ((old + 1u) % NBLK == 0u) ? 1 : 0;
    }
    __syncthreads();

    // ---- last finishing block reduces all partials and writes the scalar ----
    if (done) {
        __threadfence();   // acquire
        double t = 0.0;
        for (int i = threadIdx.x; i < NBLK; i += 256) {
            // atomic RMW read: coherent across XCDs regardless of L2 state
            unsigned long long bits =
                atomicAdd((unsigned long long*)(partials + i), 0ULL);
            t += __longlong_as_double((long long)bits);
        }
        #pragma unroll
        for (int o = 32; o > 0; o >>= 1) t += __shfl_down(t, o, 64);
        if (lane == 0) s[wid] = t;
        __syncthreads();
        if (threadIdx.x == 0)
            final_out[0] = (float)((s[0] + s[1] + s[2] + s[3]) / (double)BB);
    }
}

extern "C" void kernel_launch(void* const* d_in, const int* in_sizes, int n_in,
                              void* d_out, int out_size, void* d_ws, size_t ws_size,
                              hipStream_t stream) {
    const float* output  = (const float*)d_in[0];
    const float* boxes   = (const float*)d_in[1];
    const int*   cls     = (const int*)d_in[2];
    const float* anchors = (const float*)d_in[3];
    float* out = (float*)d_out;
    double* partials = (double*)d_ws;                          // NBLK doubles
    unsigned int* cnt = (unsigned int*)((char*)d_ws + NBLK * sizeof(double));

    fused_kernel<<<NBLK, 256, 0, stream>>>(output, boxes, cls, anchors,
                                           partials, cnt, out);
}

// Round 7
// 22.175 us; speedup vs baseline: 2.9048x; 2.9048x over previous
//
#include <hip/hip_runtime.h>

#define IMGSZ 448.0f
#define HH 28
#define WW 28
#define AA 5
#define CC 80
#define BB 128
#define NN 50
#define HW (HH * WW)
#define NCELL (BB * AA * HW)          // 501760
#define NBOX  (BB * NN)               // 6400
#define NOOBJ_BLKS 256                // grid-stride blocks for conf channel
#define BOX_BLKS  (NBOX / 4)          // 1600 (4 waves/block, 1 box/wave)
#define NBLK (NOOBJ_BLKS + BOX_BLKS)  // 1856
#define SEGQ (HW / 4)                 // 196 float4s per (b,a) conf channel

__device__ __forceinline__ float sigf(float x) {
    return 1.0f / (1.0f + __expf(-x));
}

// compute (best_anchor, gi, gj) for one box
__device__ __forceinline__ int cell_of(const float* __restrict__ anc,
                                       float bx, float by, float bw, float bh,
                                       int* pgi, int* pgj) {
    float gtw = bw * IMGSZ, gth = bh * IMGSZ;
    float gt_area = gtw * gth;
    int best = 0;
    float best_iou = -1.0f;
    #pragma unroll
    for (int k = 0; k < AA; ++k) {
        float aw = anc[2 * k], ah = anc[2 * k + 1];
        float inter = fminf(gtw, aw) * fminf(gth, ah);
        float iou = inter / (gt_area + aw * ah - inter);
        if (iou > best_iou) { best_iou = iou; best = k; }
    }
    float gx = bx * WW, gy = by * HH;
    int gi = (int)gx; gi = gi < 0 ? 0 : (gi > WW - 1 ? WW - 1 : gi);
    int gj = (int)gy; gj = gj < 0 ? 0 : (gj > HH - 1 ? HH - 1 : gj);
    *pgi = gi; *pgj = gj;
    return best;
}

// ---- kernel 1: fused noobj + wave-per-box; NO atomics, one partial/block ----
__global__ void fused_kernel(const float* __restrict__ out,
                             const float* __restrict__ boxes,
                             const int* __restrict__ cls,
                             const float* __restrict__ anchors,
                             double* __restrict__ partials) {
    double v = 0.0;
    int blk = blockIdx.x;

    if (blk < NOOBJ_BLKS) {
        // noobj baseline: 0.5*sigmoid(conf)^2 over all cells, float4 grid-stride
        // NCELL/4 = 125440 float4s total; SEGQ = 196 float4s per (b,a) segment
        const int NQ = NCELL / 4;
        for (int q = blk * 256 + threadIdx.x; q < NQ; q += NOOBJ_BLKS * 256) {
            int seg = q / SEGQ;            // which (b,a), 0..639
            int off = q - seg * SEGQ;      // float4 offset within conf channel
            const float4* p = (const float4*)(out + ((size_t)seg * 85 + 4) * HW) + off;
            float4 x = *p;
            float s0 = sigf(x.x), s1 = sigf(x.y), s2 = sigf(x.z), s3 = sigf(x.w);
            v += 0.5 * (double)(s0 * s0) + 0.5 * (double)(s1 * s1)
               + 0.5 * (double)(s2 * s2) + 0.5 * (double)(s3 * s3);
        }
    } else {
        // one wave per GT box: 4 waves/block
        int lane = threadIdx.x & 63;
        int u = (blk - NOOBJ_BLKS) * 4 + (threadIdx.x >> 6);   // box idx < 6400
        int b = u / NN, n = u - b * NN;

        float anc[2 * AA];
        #pragma unroll
        for (int i = 0; i < 2 * AA; ++i) anc[i] = anchors[i];

        const float* bx0 = boxes + (size_t)u * 4;
        float bx = bx0[0], by = bx0[1], bw = bx0[2], bh = bx0[3];
        int gi, gj;
        int best = cell_of(anc, bx, by, bw, bh, &gi, &gj);

        // ---- issue ALL scattered loads for this box NOW (always safe) ----
        size_t base = ((size_t)(b * AA + best) * 85) * HW + (size_t)gj * WW + gi;
        const float* cl = out + base + 5 * HW;
        float val0 = cl[(size_t)lane * HW];                           // classes 0..63
        float val1 = (lane < 16) ? cl[(size_t)(64 + lane) * HW] : -3.4e38f; // 64..79
        float pch  = (lane < 5) ? out[base + (size_t)lane * HW] : 0.0f;     // tx..conf
        int tc = cls[u];

        // ---- dedup while loads are in flight (last-write-wins) ----
        bool conflict = false;
        int n2 = n + 1 + lane;
        if (n2 < NN) {
            const float* bp = boxes + (size_t)(b * NN + n2) * 4;
            int gi2, gj2;
            int best2 = cell_of(anc, bp[0], bp[1], bp[2], bp[3], &gi2, &gj2);
            conflict = (best2 == best && gi2 == gi && gj2 == gj);
        }
        bool alive = (__ballot(conflict) == 0ULL);

        if (alive) {
            // 80-class log-softmax, lane-parallel
            float m = fmaxf(val0, val1);
            #pragma unroll
            for (int o = 32; o > 0; o >>= 1) m = fmaxf(m, __shfl_xor(m, o, 64));
            float se = __expf(val0 - m) + ((lane < 16) ? __expf(val1 - m) : 0.0f);
            #pragma unroll
            for (int o = 32; o > 0; o >>= 1) se += __shfl_xor(se, o, 64);
            float lse = m + logf(se);

            float contrib = 0.0f;
            if (lane == 0)       contrib += lse;   // nll = lse - logit_tc
            if (tc == lane)      contrib -= val0;
            if (tc == 64 + lane) contrib -= val1;  // only lanes <16 can hit

            if (lane < 5) {
                if (lane == 0) {
                    float ptx = sigf(pch), tx = bx * WW - (float)gi;
                    contrib += 5.0f * (ptx - tx) * (ptx - tx);
                } else if (lane == 1) {
                    float pty = sigf(pch), ty = by * HH - (float)gj;
                    contrib += 5.0f * (pty - ty) * (pty - ty);
                } else if (lane == 2) {
                    float tw = logf(bw * WW / (anc[2 * best] / 16.0f) + 1e-16f);
                    contrib += 5.0f * (pch - tw) * (pch - tw);
                } else if (lane == 3) {
                    float th = logf(bh * HH / (anc[2 * best + 1] / 16.0f) + 1e-16f);
                    contrib += 5.0f * (pch - th) * (pch - th);
                } else {
                    float pc = sigf(pch);
                    // obj conf term minus the noobj 0.5*pc^2 added by baseline
                    contrib += (pc - 1.0f) * (pc - 1.0f) - 0.5f * pc * pc;
                }
            }
            v = (double)contrib;
        }
    }

    // block reduction (4 waves of 64); ONE plain store per block, no atomics
    #pragma unroll
    for (int o = 32; o > 0; o >>= 1) v += __shfl_down(v, o, 64);
    __shared__ double s[4];
    int lane = threadIdx.x & 63, wid = threadIdx.x >> 6;
    if (lane == 0) s[wid] = v;
    __syncthreads();
    if (threadIdx.x == 0)
        partials[blk] = s[0] + s[1] + s[2] + s[3];
}

// ---- kernel 2: reduce 1856 partials, divide by B, write scalar ----
__global__ void final_kernel(const double* __restrict__ partials,
                             float* __restrict__ out) {
    double v = 0.0;
    for (int i = threadIdx.x; i < NBLK; i += 256) v += partials[i];
    #pragma unroll
    for (int o = 32; o > 0; o >>= 1) v += __shfl_down(v, o, 64);
    __shared__ double s[4];
    int lane = threadIdx.x & 63, wid = threadIdx.x >> 6;
    if (lane == 0) s[wid] = v;
    __syncthreads();
    if (threadIdx.x == 0)
        out[0] = (float)((s[0] + s[1] + s[2] + s[3]) / (double)BB);
}

extern "C" void kernel_launch(void* const* d_in, const int* in_sizes, int n_in,
                              void* d_out, int out_size, void* d_ws, size_t ws_size,
                              hipStream_t stream) {
    const float* output  = (const float*)d_in[0];
    const float* boxes   = (const float*)d_in[1];
    const int*   cls     = (const int*)d_in[2];
    const float* anchors = (const float*)d_in[3];
    float* out = (float*)d_out;
    double* partials = (double*)d_ws;

    fused_kernel<<<NBLK, 256, 0, stream>>>(output, boxes, cls, anchors, partials);
    final_kernel<<<1, 256, 0, stream>>>(partials, out);
}